// Round 1
// baseline (3562.118 us; speedup 1.0000x reference)
//
#include <hip/hip_runtime.h>
#include <math.h>

#define S_CTX 2048
#define DMODEL 1024
#define NHEAD 16
#define HD 64
#define BATCH 4
#define DFF 4096

// ---------------------------------------------------------------------------
// GELU (tanh approximation, matches reference exactly in structure)
// ---------------------------------------------------------------------------
__device__ __forceinline__ float gelu_f(float v) {
    const float c = 0.7978845608028654f; // sqrt(2/pi)
    float u = c * (v + 0.044715f * v * v * v);
    return 0.5f * v * (1.0f + tanhf(u));
}

// ---------------------------------------------------------------------------
// SGEMM: C[M,N] = A[M,K] @ B[K,N] + bias[N]  (optional GELU epilogue)
// fp32 vector-ALU GEMM. BM=BN=128, BK=8, 256 threads, 8x8 microtile.
// M,N multiples of 128; K multiple of 8 (true for all 4 calls).
// ---------------------------------------------------------------------------
template<int GELU>
__global__ __launch_bounds__(256)
void gemm_bias_kernel(const float* __restrict__ A, const float* __restrict__ B,
                      const float* __restrict__ bias, float* __restrict__ C,
                      int M, int N, int K)
{
    __shared__ float As[8][132];   // [k][row], pad to 132 for bank spread
    __shared__ float Bs[8][132];   // [k][col]

    const int tid = threadIdx.x;
    const int tx  = tid & 15;      // 0..15 -> col strips 4*tx and 64+4*tx
    const int ty  = tid >> 4;      // 0..15 -> row strips 4*ty and 64+4*ty
    const int m0  = blockIdx.y * 128;
    const int n0  = blockIdx.x * 128;

    // staging assignments
    const int arow = tid >> 1;         // 0..127
    const int acol = (tid & 1) * 4;    // 0 or 4
    const int brow = tid >> 5;         // 0..7
    const int bcol = (tid & 31) * 4;   // 0..124

    const float* Ap = A + (size_t)(m0 + arow) * K + acol;
    const float* Bp = B + (size_t)brow * N + n0 + bcol;

    float acc[8][8];
    #pragma unroll
    for (int i = 0; i < 8; ++i)
        #pragma unroll
        for (int j = 0; j < 8; ++j) acc[i][j] = 0.0f;

    for (int k0 = 0; k0 < K; k0 += 8) {
        const float4 av = *(const float4*)(Ap + k0);
        const float4 bv = *(const float4*)(Bp + (size_t)k0 * N);
        __syncthreads();   // previous iteration's LDS reads complete
        As[acol + 0][arow] = av.x;
        As[acol + 1][arow] = av.y;
        As[acol + 2][arow] = av.z;
        As[acol + 3][arow] = av.w;
        *(float4*)&Bs[brow][bcol] = bv;
        __syncthreads();

        #pragma unroll
        for (int kk = 0; kk < 8; ++kk) {
            const float4 a0 = *(const float4*)&As[kk][ty * 4];
            const float4 a1 = *(const float4*)&As[kk][64 + ty * 4];
            const float4 b0 = *(const float4*)&Bs[kk][tx * 4];
            const float4 b1 = *(const float4*)&Bs[kk][64 + tx * 4];
            const float ar[8] = {a0.x, a0.y, a0.z, a0.w, a1.x, a1.y, a1.z, a1.w};
            const float br[8] = {b0.x, b0.y, b0.z, b0.w, b1.x, b1.y, b1.z, b1.w};
            #pragma unroll
            for (int i = 0; i < 8; ++i)
                #pragma unroll
                for (int j = 0; j < 8; ++j)
                    acc[i][j] = fmaf(ar[i], br[j], acc[i][j]);
        }
    }

    const float4 bv0 = *(const float4*)&bias[n0 + tx * 4];
    const float4 bv1 = *(const float4*)&bias[n0 + 64 + tx * 4];
    const float bb0[4] = {bv0.x, bv0.y, bv0.z, bv0.w};
    const float bb1[4] = {bv1.x, bv1.y, bv1.z, bv1.w};

    #pragma unroll
    for (int i = 0; i < 8; ++i) {
        const int r = (i < 4) ? (ty * 4 + i) : (64 + ty * 4 + (i - 4));
        float* crow = C + (size_t)(m0 + r) * N + n0;
        float o0[4], o1[4];
        #pragma unroll
        for (int j = 0; j < 4; ++j) {
            float v0 = acc[i][j]     + bb0[j];
            float v1 = acc[i][j + 4] + bb1[j];
            if (GELU) { v0 = gelu_f(v0); v1 = gelu_f(v1); }
            o0[j] = v0; o1[j] = v1;
        }
        *(float4*)(crow + tx * 4)      = make_float4(o0[0], o0[1], o0[2], o0[3]);
        *(float4*)(crow + 64 + tx * 4) = make_float4(o1[0], o1[1], o1[2], o1[3]);
    }
}

// ---------------------------------------------------------------------------
// Flash-style causal attention. qkv layout [B, S, 3*D]; q|k|v each D wide,
// head h occupies cols h*64..h*64+63 within its third.
// One block = one (b, h, 64-row q-tile). 256 threads, 4x4 microtiles.
// Output: merged heads [B, S, D].
// ---------------------------------------------------------------------------
__global__ __launch_bounds__(256)
void attn_kernel(const float* __restrict__ qkv, float* __restrict__ out)
{
    __shared__ float Qst[64][68];  // [dim][row]   (transposed)
    __shared__ float Kst[64][68];  // [dim][key]   (transposed)
    __shared__ float Vs [64][68];  // [key][dim]   (natural)
    __shared__ float Ps [64][68];  // [row][key]

    const int tid = threadIdx.x;
    const int tx  = tid & 15;   // key/dim strip
    const int ty  = tid >> 4;   // q-row strip
    const int qt  = blockIdx.x;
    const int h   = blockIdx.y;
    const int b   = blockIdx.z;
    const int q0  = qt * 64;

    // ---- load Q tile transposed ----
    {
        const int r = tid >> 2;            // 0..63
        const int dbase = (tid & 3) * 4;   // 0,4,8,12
        const float* qp = qkv + ((size_t)b * S_CTX + q0 + r) * (3 * DMODEL) + h * HD + dbase;
        #pragma unroll
        for (int c = 0; c < 4; ++c) {
            const float4 v = *(const float4*)(qp + 16 * c);
            Qst[dbase + 16 * c + 0][r] = v.x;
            Qst[dbase + 16 * c + 1][r] = v.y;
            Qst[dbase + 16 * c + 2][r] = v.z;
            Qst[dbase + 16 * c + 3][r] = v.w;
        }
    }

    float m_i[4], l_i[4], acc[4][4];
    #pragma unroll
    for (int i = 0; i < 4; ++i) {
        m_i[i] = -1e30f; l_i[i] = 0.0f;
        #pragma unroll
        for (int j = 0; j < 4; ++j) acc[i][j] = 0.0f;
    }

    const int nkt = qt + 1;   // causal: key tiles 0..qt
    for (int kt = 0; kt < nkt; ++kt) {
        const int k0 = kt * 64;
        __syncthreads();   // previous iteration's Kst/Vs/Ps reads complete
        {
            const int r = tid >> 2;
            const int dbase = (tid & 3) * 4;
            const float* kp = qkv + ((size_t)b * S_CTX + k0 + r) * (3 * DMODEL) + DMODEL + h * HD + dbase;
            const float* vp = kp + DMODEL;
            #pragma unroll
            for (int c = 0; c < 4; ++c) {
                const float4 kv = *(const float4*)(kp + 16 * c);
                Kst[dbase + 16 * c + 0][r] = kv.x;
                Kst[dbase + 16 * c + 1][r] = kv.y;
                Kst[dbase + 16 * c + 2][r] = kv.z;
                Kst[dbase + 16 * c + 3][r] = kv.w;
                const float4 vv = *(const float4*)(vp + 16 * c);
                *(float4*)&Vs[r][dbase + 16 * c] = vv;
            }
        }
        __syncthreads();

        // ---- scores S = Q K^T ----
        float s[4][4];
        #pragma unroll
        for (int i = 0; i < 4; ++i)
            #pragma unroll
            for (int j = 0; j < 4; ++j) s[i][j] = 0.0f;

        #pragma unroll 8
        for (int kk = 0; kk < 64; ++kk) {
            const float4 qa = *(const float4*)&Qst[kk][ty * 4];
            const float4 ka = *(const float4*)&Kst[kk][tx * 4];
            const float qr[4] = {qa.x, qa.y, qa.z, qa.w};
            const float kr[4] = {ka.x, ka.y, ka.z, ka.w};
            #pragma unroll
            for (int i = 0; i < 4; ++i)
                #pragma unroll
                for (int j = 0; j < 4; ++j)
                    s[i][j] = fmaf(qr[i], kr[j], s[i][j]);
        }

        // ---- scale + causal mask ----
        #pragma unroll
        for (int i = 0; i < 4; ++i) {
            const int qi = q0 + ty * 4 + i;
            #pragma unroll
            for (int j = 0; j < 4; ++j) {
                const int ki = k0 + tx * 4 + j;
                s[i][j] = (ki <= qi) ? s[i][j] * 0.125f : -1e30f;
            }
        }

        // ---- online softmax (row groups = 16 consecutive lanes, tx axis) ----
        float p[4][4];
        #pragma unroll
        for (int i = 0; i < 4; ++i) {
            float rmax = fmaxf(fmaxf(s[i][0], s[i][1]), fmaxf(s[i][2], s[i][3]));
            rmax = fmaxf(rmax, __shfl_xor(rmax, 1));
            rmax = fmaxf(rmax, __shfl_xor(rmax, 2));
            rmax = fmaxf(rmax, __shfl_xor(rmax, 4));
            rmax = fmaxf(rmax, __shfl_xor(rmax, 8));
            const float mnew  = fmaxf(m_i[i], rmax);
            const float scale = __expf(m_i[i] - mnew);
            float rs = 0.0f;
            #pragma unroll
            for (int j = 0; j < 4; ++j) {
                p[i][j] = __expf(s[i][j] - mnew);
                rs += p[i][j];
            }
            rs += __shfl_xor(rs, 1);
            rs += __shfl_xor(rs, 2);
            rs += __shfl_xor(rs, 4);
            rs += __shfl_xor(rs, 8);
            l_i[i] = l_i[i] * scale + rs;
            m_i[i] = mnew;
            #pragma unroll
            for (int j = 0; j < 4; ++j) acc[i][j] *= scale;
        }

        // ---- P to LDS, then O += P @ V ----
        #pragma unroll
        for (int i = 0; i < 4; ++i)
            *(float4*)&Ps[ty * 4 + i][tx * 4] = make_float4(p[i][0], p[i][1], p[i][2], p[i][3]);
        __syncthreads();

        #pragma unroll 8
        for (int kk = 0; kk < 64; ++kk) {
            const float4 vv = *(const float4*)&Vs[kk][tx * 4];
            const float vr[4] = {vv.x, vv.y, vv.z, vv.w};
            const float pr0 = Ps[ty * 4 + 0][kk];
            const float pr1 = Ps[ty * 4 + 1][kk];
            const float pr2 = Ps[ty * 4 + 2][kk];
            const float pr3 = Ps[ty * 4 + 3][kk];
            #pragma unroll
            for (int j = 0; j < 4; ++j) {
                acc[0][j] = fmaf(pr0, vr[j], acc[0][j]);
                acc[1][j] = fmaf(pr1, vr[j], acc[1][j]);
                acc[2][j] = fmaf(pr2, vr[j], acc[2][j]);
                acc[3][j] = fmaf(pr3, vr[j], acc[3][j]);
            }
        }
    }

    // ---- normalize and write merged-head output ----
    #pragma unroll
    for (int i = 0; i < 4; ++i) {
        const float inv = 1.0f / l_i[i];
        float* op = out + ((size_t)b * S_CTX + q0 + ty * 4 + i) * DMODEL + h * HD + tx * 4;
        *(float4*)op = make_float4(acc[i][0] * inv, acc[i][1] * inv,
                                   acc[i][2] * inv, acc[i][3] * inv);
    }
}

// ---------------------------------------------------------------------------
// Fused residual + LayerNorm: out = g * normalize(in1 + in2) + b
// One block (256 threads) per row of D=1024. Each thread owns 4 elements.
// ---------------------------------------------------------------------------
__global__ __launch_bounds__(256)
void ln_res_kernel(const float* __restrict__ in1, const float* __restrict__ in2,
                   const float* __restrict__ g, const float* __restrict__ bb,
                   float* __restrict__ out)
{
    const int row = blockIdx.x;
    const int tid = threadIdx.x;
    const size_t base = (size_t)row * DMODEL + tid * 4;

    const float4 x1 = *(const float4*)(in1 + base);
    const float4 x2 = *(const float4*)(in2 + base);
    const float y0 = x1.x + x2.x, y1 = x1.y + x2.y;
    const float y2 = x1.z + x2.z, y3 = x1.w + x2.w;

    float s1 = y0 + y1 + y2 + y3;
    float s2 = y0 * y0 + y1 * y1 + y2 * y2 + y3 * y3;
    #pragma unroll
    for (int off = 1; off < 64; off <<= 1) {
        s1 += __shfl_xor(s1, off);
        s2 += __shfl_xor(s2, off);
    }
    __shared__ float red[8];
    if ((tid & 63) == 0) {
        red[tid >> 6]     = s1;
        red[4 + (tid >> 6)] = s2;
    }
    __syncthreads();
    s1 = red[0] + red[1] + red[2] + red[3];
    s2 = red[4] + red[5] + red[6] + red[7];

    const float mean = s1 * (1.0f / DMODEL);
    const float var  = s2 * (1.0f / DMODEL) - mean * mean;
    const float rstd = rsqrtf(var + 1e-5f);

    const float4 g4 = *(const float4*)(g + tid * 4);
    const float4 b4 = *(const float4*)(bb + tid * 4);
    float4 o;
    o.x = g4.x * ((y0 - mean) * rstd) + b4.x;
    o.y = g4.y * ((y1 - mean) * rstd) + b4.y;
    o.z = g4.z * ((y2 - mean) * rstd) + b4.z;
    o.w = g4.w * ((y3 - mean) * rstd) + b4.w;
    *(float4*)(out + base) = o;
}

// ---------------------------------------------------------------------------
// kernel_launch
// ---------------------------------------------------------------------------
extern "C" void kernel_launch(void* const* d_in, const int* in_sizes, int n_in,
                              void* d_out, int out_size, void* d_ws, size_t ws_size,
                              hipStream_t stream)
{
    const float* x       = (const float*)d_in[0];
    const float* w_attn  = (const float*)d_in[1];
    const float* b_attn  = (const float*)d_in[2];
    const float* w_aproj = (const float*)d_in[3];
    const float* b_aproj = (const float*)d_in[4];
    const float* g1      = (const float*)d_in[5];
    const float* b1      = (const float*)d_in[6];
    const float* w_fc    = (const float*)d_in[7];
    const float* b_fc    = (const float*)d_in[8];
    const float* w_mproj = (const float*)d_in[9];
    const float* b_mproj = (const float*)d_in[10];
    const float* g2      = (const float*)d_in[11];
    const float* b2      = (const float*)d_in[12];
    float* outp = (float*)d_out;

    // Workspace layout (floats). Total needed: 41,943,040 floats = 167.8 MB.
    //   qkv : [0,            25165824)   -- [8192, 3072]
    //   a   : [25165824,     33554432)   -- [8192, 1024] attention out
    //   t   : [33554432,     41943040)   -- [8192, 1024] proj scratch (reused)
    //   h   : [0,            33554432)   -- [8192, 4096] reuses dead qkv+a
    //   n   : d_out                      -- ln1 output, final LN overwrites in place
    float* ws  = (float*)d_ws;
    float* qkv = ws;
    float* a   = ws + 25165824;
    float* t   = ws + 33554432;
    float* h   = ws;
    float* n   = outp;

    const int M = BATCH * S_CTX;  // 8192

    // 1) qkv = x @ w_attn + b_attn
    gemm_bias_kernel<0><<<dim3(3 * DMODEL / 128, M / 128), 256, 0, stream>>>(
        x, w_attn, b_attn, qkv, M, 3 * DMODEL, DMODEL);

    // 2) a = causal_attention(qkv), merged heads
    attn_kernel<<<dim3(S_CTX / 64, NHEAD, BATCH), 256, 0, stream>>>(qkv, a);

    // 3) t = a @ w_aproj + b_aproj
    gemm_bias_kernel<0><<<dim3(DMODEL / 128, M / 128), 256, 0, stream>>>(
        a, w_aproj, b_aproj, t, M, DMODEL, DMODEL);

    // 4) n = LayerNorm(x + t; g1, b1)
    ln_res_kernel<<<M, 256, 0, stream>>>(x, t, g1, b1, n);

    // 5) h = gelu(n @ w_fc + b_fc)
    gemm_bias_kernel<1><<<dim3(DFF / 128, M / 128), 256, 0, stream>>>(
        n, w_fc, b_fc, h, M, DFF, DMODEL);

    // 6) t = h @ w_mproj + b_mproj
    gemm_bias_kernel<0><<<dim3(DMODEL / 128, M / 128), 256, 0, stream>>>(
        h, w_mproj, b_mproj, t, M, DMODEL, DFF);

    // 7) out = LayerNorm(n + t; g2, b2)   (n == d_out, safe in-place per-row)
    ln_res_kernel<<<M, 256, 0, stream>>>(n, t, g2, b2, outp);
}

// Round 4
// 768.986 us; speedup vs baseline: 4.6322x; 4.6322x over previous
//
#include <hip/hip_runtime.h>
#include <math.h>

#define S_CTX 2048
#define DMODEL 1024
#define NHEAD 16
#define HD 64
#define BATCH 4
#define DFF 4096

typedef __bf16 bf16x8 __attribute__((ext_vector_type(8)));
typedef float f32x4 __attribute__((ext_vector_type(4)));

// fp32 -> bf16 (round-to-nearest-even), bit-level
__device__ __forceinline__ unsigned short f2bf(float f) {
    union { float f; unsigned int u; } v; v.f = f;
    unsigned int u = v.u;
    u += 0x7fffu + ((u >> 16) & 1u);
    return (unsigned short)(u >> 16);
}

__device__ __forceinline__ float gelu_f(float v) {
    const float c = 0.7978845608028654f; // sqrt(2/pi)
    float u = c * (v + 0.044715f * v * v * v);
    return 0.5f * v * (1.0f + tanhf(u));
}

// async global->LDS, 16 bytes per lane; LDS dest = wave-uniform base + lane*16
#define GLOAD16(gsrc, ldst)                                                     \
    __builtin_amdgcn_global_load_lds(                                           \
        (const __attribute__((address_space(1))) void*)(gsrc),                  \
        (__attribute__((address_space(3))) void*)(ldst), 16, 0, 0)

// ---------------------------------------------------------------------------
// Weight cast+transpose: W fp32 [K,N] -> WT bf16 [N,K]
// ---------------------------------------------------------------------------
__global__ __launch_bounds__(256)
void wcast_kernel(const float* __restrict__ W, short* __restrict__ WT, int K, int N)
{
    __shared__ float tile[32][33];
    const int n0 = blockIdx.x * 32;
    const int k0 = blockIdx.y * 32;
    {
        const int r  = threadIdx.x >> 3;
        const int c4 = (threadIdx.x & 7) * 4;
        const float4 v = *(const float4*)&W[(size_t)(k0 + r) * N + n0 + c4];
        tile[r][c4 + 0] = v.x; tile[r][c4 + 1] = v.y;
        tile[r][c4 + 2] = v.z; tile[r][c4 + 3] = v.w;
    }
    __syncthreads();
    const int n  = threadIdx.x >> 3;
    const int k4 = (threadIdx.x & 7) * 4;
    ushort4 o = make_ushort4(f2bf(tile[k4 + 0][n]), f2bf(tile[k4 + 1][n]),
                             f2bf(tile[k4 + 2][n]), f2bf(tile[k4 + 3][n]));
    *(ushort4*)&WT[(size_t)(n0 + n) * K + k0 + k4] = o;
}

// ---------------------------------------------------------------------------
// Activation cast: fp32 -> bf16, vectorized
// ---------------------------------------------------------------------------
__global__ __launch_bounds__(256)
void cast_act_kernel(const float* __restrict__ in, short* __restrict__ out, int n4)
{
    int idx = blockIdx.x * blockDim.x + threadIdx.x;
    const int stride = gridDim.x * blockDim.x;
    for (; idx < n4; idx += stride) {
        const float4 v = ((const float4*)in)[idx];
        ((ushort4*)out)[idx] = make_ushort4(f2bf(v.x), f2bf(v.y), f2bf(v.z), f2bf(v.w));
    }
}

// ---------------------------------------------------------------------------
// bf16 MFMA GEMM (m97 structure): C[M,N] = A[M,K] @ BT[N,K]^T + bias
// 128x128 tile, BK=32, 4 waves, 4x4 frags of 16x16x32. global_load_lds(16B)
// with pre-swizzled source (rule #21), XOR-swizzled ds_read_b128.
// ---------------------------------------------------------------------------
template<int GELU, int OBF16>
__global__ __launch_bounds__(256)
void mfma_gemm_kernel(const short* __restrict__ Ab, const short* __restrict__ BTb,
                      const float* __restrict__ bias, void* __restrict__ Cout,
                      int M, int N, int K)
{
    __shared__ short As[128 * 32];
    __shared__ short Bs[128 * 32];

    const int tid  = threadIdx.x;
    const int lane = tid & 63;
    const int wave = tid >> 6;
    const int wr   = (wave >> 1) * 64;
    const int wc   = (wave & 1) * 64;
    const int m0   = blockIdx.y * 128;
    const int n0   = blockIdx.x * 128;

    const int lrow = tid >> 2;           // 0..63
    const int slot = tid & 3;
    const int sw   = slot ^ (lrow & 3);  // pre-swizzled global source slot
    const short* Ag0 = Ab  + (size_t)(m0 + lrow) * K      + sw * 8;
    const short* Ag1 = Ab  + (size_t)(m0 + 64 + lrow) * K + sw * 8;
    const short* Bg0 = BTb + (size_t)(n0 + lrow) * K      + sw * 8;
    const short* Bg1 = BTb + (size_t)(n0 + 64 + lrow) * K + sw * 8;

    short* AsW = As + wave * 512;        // +2048 shorts = +4096 B = row 64
    short* BsW = Bs + wave * 512;

    f32x4 acc[4][4];
    #pragma unroll
    for (int i = 0; i < 4; ++i)
        #pragma unroll
        for (int j = 0; j < 4; ++j) acc[i][j] = (f32x4){0.f, 0.f, 0.f, 0.f};

    const int r  = lane & 15;
    const int kg = lane >> 4;
    int aoff[4], boff[4];
    #pragma unroll
    for (int m = 0; m < 4; ++m) {
        const int arow = wr + m * 16 + r;
        aoff[m] = arow * 32 + (kg ^ (arow & 3)) * 8;
        const int bcol = wc + m * 16 + r;
        boff[m] = bcol * 32 + (kg ^ (bcol & 3)) * 8;
    }

    for (int k0 = 0; k0 < K; k0 += 32) {
        __syncthreads();
        GLOAD16(Ag0 + k0, AsW);
        GLOAD16(Ag1 + k0, AsW + 2048);
        GLOAD16(Bg0 + k0, BsW);
        GLOAD16(Bg1 + k0, BsW + 2048);
        __syncthreads();

        bf16x8 af[4], bfr[4];
        #pragma unroll
        for (int m = 0; m < 4; ++m) af[m]  = *(const bf16x8*)(As + aoff[m]);
        #pragma unroll
        for (int n = 0; n < 4; ++n) bfr[n] = *(const bf16x8*)(Bs + boff[n]);
        #pragma unroll
        for (int m = 0; m < 4; ++m)
            #pragma unroll
            for (int n = 0; n < 4; ++n)
                acc[m][n] = __builtin_amdgcn_mfma_f32_16x16x32_bf16(
                    af[m], bfr[n], acc[m][n], 0, 0, 0);
    }

    // D: row = (lane>>4)*4 + reg, col = lane&15  [m89]
    const int crow0 = m0 + wr + kg * 4;
    const int ccol0 = n0 + wc + r;
    #pragma unroll
    for (int m = 0; m < 4; ++m) {
        #pragma unroll
        for (int i = 0; i < 4; ++i) {
            const size_t row = (size_t)(crow0 + m * 16 + i);
            #pragma unroll
            for (int n = 0; n < 4; ++n) {
                float v = acc[m][n][i] + bias[ccol0 + n * 16];
                if (GELU) v = gelu_f(v);
                if (OBF16) ((short*)Cout)[row * N + ccol0 + n * 16] = (short)f2bf(v);
                else       ((float*)Cout)[row * N + ccol0 + n * 16] = v;
            }
        }
    }
}

// ---------------------------------------------------------------------------
// MFMA flash attention (bf16 inputs, fp32 softmax/accum, bf16 out).
// qkvb: [B, S, 3*D] bf16. Block = (b, h, 64-row q-tile), 4 waves; each wave
// owns 16 q-rows. K-tile = 64 keys. Q/K staged via global_load_lds with
// slot^(row&7) swizzle; V transpose-staged Vt[d][key]; P via per-wave LDS.
// ---------------------------------------------------------------------------
__global__ __launch_bounds__(256)
void attn_mfma_kernel(const short* __restrict__ qkvb, short* __restrict__ out)
{
    __shared__ short Qs[64 * 64];      // [q][d]   128B rows, 8 slots
    __shared__ short Ks[64 * 64];      // [key][d]
    __shared__ short Vt[64 * 64];      // [d][key]
    __shared__ short Pl[4][16 * 72];   // per-wave P, padded rows (144B = 9x16B)

    const int tid  = threadIdx.x;
    const int lane = tid & 63;
    const int wave = tid >> 6;
    const int qt = blockIdx.x, h = blockIdx.y, b = blockIdx.z;
    const int q0 = qt * 64;

    const int r  = lane & 15;
    const int kg = lane >> 4;
    const size_t rstr = 3 * DMODEL;    // qkv row stride (elements)

    // ---- stage Q once: per wave rows wave*16 + rr*8 + (lane>>3), slot lane&7
    {
        const short* qbase = qkvb + ((size_t)(b * S_CTX + q0)) * rstr + h * HD;
        #pragma unroll
        for (int rr = 0; rr < 2; ++rr) {
            const int rl = wave * 16 + rr * 8 + (lane >> 3);
            const int sl = lane & 7;
            GLOAD16(qbase + (size_t)rl * rstr + ((sl ^ (rl & 7)) * 8),
                    Qs + wave * 1024 + rr * 512);
        }
    }

    float m_i[4], l_i[4];
    f32x4 o[4];
    #pragma unroll
    for (int i = 0; i < 4; ++i) {
        m_i[i] = -1e30f; l_i[i] = 0.0f;
        o[i] = (f32x4){0.f, 0.f, 0.f, 0.f};
    }

    for (int kt = 0; kt <= qt; ++kt) {
        const int k0 = kt * 64;
        __syncthreads();   // Q ready (iter 0); prior-iter K/V/P reads done

        // ---- stage K (async, swizzled source) ----
        {
            const short* kbase = qkvb + ((size_t)(b * S_CTX + k0)) * rstr + DMODEL + h * HD;
            #pragma unroll
            for (int rr = 0; rr < 2; ++rr) {
                const int rl = wave * 16 + rr * 8 + (lane >> 3);
                const int sl = lane & 7;
                GLOAD16(kbase + (size_t)rl * rstr + ((sl ^ (rl & 7)) * 8),
                        Ks + wave * 1024 + rr * 512);
            }
        }
        // ---- stage V transposed: Vt[d][key], swizzled ----
        {
            const int d0 = (tid & 15) * 4;
            const int kb = (tid >> 4) * 4;
            const short* vsrc = qkvb + ((size_t)(b * S_CTX + k0 + kb)) * rstr
                                + 2 * DMODEL + h * HD + d0;
            const ushort4 r0 = *(const ushort4*)(vsrc);
            const ushort4 r1 = *(const ushort4*)(vsrc + rstr);
            const ushort4 r2 = *(const ushort4*)(vsrc + 2 * rstr);
            const ushort4 r3 = *(const ushort4*)(vsrc + 3 * rstr);
            const unsigned short e0[4] = {r0.x, r0.y, r0.z, r0.w};
            const unsigned short e1[4] = {r1.x, r1.y, r1.z, r1.w};
            const unsigned short e2[4] = {r2.x, r2.y, r2.z, r2.w};
            const unsigned short e3[4] = {r3.x, r3.y, r3.z, r3.w};
            #pragma unroll
            for (int dd = 0; dd < 4; ++dd) {
                const int d = d0 + dd;
                const int byteoff = d * 128 + (((kb >> 3) ^ (d & 7)) * 16) + ((kb & 4) * 2);
                *(ushort4*)((char*)Vt + byteoff) = make_ushort4(e0[dd], e1[dd], e2[dd], e3[dd]);
            }
        }
        __syncthreads();   // staging visible (vmcnt+lgkm drained by barrier)

        // ---- S = Q K^T : wave's 16 q-rows x 64 keys, 8 MFMA ----
        f32x4 s4[4];
        #pragma unroll
        for (int c = 0; c < 4; ++c) s4[c] = (f32x4){0.f, 0.f, 0.f, 0.f};
        #pragma unroll
        for (int kb2 = 0; kb2 < 2; ++kb2) {
            const int qrow = wave * 16 + r;
            const bf16x8 af = *(const bf16x8*)(Qs + qrow * 64 +
                                (((kb2 * 4 + kg) ^ (qrow & 7)) * 8));
            #pragma unroll
            for (int c = 0; c < 4; ++c) {
                const int krow = c * 16 + r;
                const bf16x8 bfv = *(const bf16x8*)(Ks + krow * 64 +
                                    (((kb2 * 4 + kg) ^ (krow & 7)) * 8));
                s4[c] = __builtin_amdgcn_mfma_f32_16x16x32_bf16(af, bfv, s4[c], 0, 0, 0);
            }
        }

        // ---- mask + online softmax; P -> per-wave LDS as bf16 ----
        const int rowg0 = q0 + wave * 16 + kg * 4;
        #pragma unroll
        for (int reg = 0; reg < 4; ++reg) {
            float sv[4];
            #pragma unroll
            for (int c = 0; c < 4; ++c) {
                const int colg = k0 + c * 16 + r;
                const float v = s4[c][reg] * 0.125f;
                sv[c] = (colg <= rowg0 + reg) ? v : -1e30f;
            }
            float rmax = fmaxf(fmaxf(sv[0], sv[1]), fmaxf(sv[2], sv[3]));
            rmax = fmaxf(rmax, __shfl_xor(rmax, 1));
            rmax = fmaxf(rmax, __shfl_xor(rmax, 2));
            rmax = fmaxf(rmax, __shfl_xor(rmax, 4));
            rmax = fmaxf(rmax, __shfl_xor(rmax, 8));
            const float mnew = fmaxf(m_i[reg], rmax);
            const float sc   = __expf(m_i[reg] - mnew);
            float rs = 0.0f;
            #pragma unroll
            for (int c = 0; c < 4; ++c) {
                const float pc = __expf(sv[c] - mnew);
                rs += pc;
                Pl[wave][(kg * 4 + reg) * 72 + c * 16 + r] = (short)f2bf(pc);
            }
            rs += __shfl_xor(rs, 1);
            rs += __shfl_xor(rs, 2);
            rs += __shfl_xor(rs, 4);
            rs += __shfl_xor(rs, 8);
            l_i[reg] = l_i[reg] * sc + rs;
            m_i[reg] = mnew;
            #pragma unroll
            for (int db = 0; db < 4; ++db) o[db][reg] *= sc;
        }

        // ---- O += P V : 8 MFMA (per-wave P, no cross-wave barrier needed) ----
        #pragma unroll
        for (int kb2 = 0; kb2 < 2; ++kb2) {
            const bf16x8 pa = *(const bf16x8*)(&Pl[wave][r * 72 + kb2 * 32 + kg * 8]);
            #pragma unroll
            for (int db = 0; db < 4; ++db) {
                const int drow = db * 16 + r;
                const bf16x8 bv = *(const bf16x8*)(Vt + drow * 64 +
                                    (((kb2 * 4 + kg) ^ (drow & 7)) * 8));
                o[db] = __builtin_amdgcn_mfma_f32_16x16x32_bf16(pa, bv, o[db], 0, 0, 0);
            }
        }
    }

    // ---- normalize, write merged-head bf16 output ----
    #pragma unroll
    for (int reg = 0; reg < 4; ++reg) {
        const float inv = 1.0f / l_i[reg];
        const size_t rowg = (size_t)(b * S_CTX) + q0 + wave * 16 + kg * 4 + reg;
        #pragma unroll
        for (int db = 0; db < 4; ++db)
            out[rowg * DMODEL + h * HD + db * 16 + r] = (short)f2bf(o[db][reg] * inv);
    }
}

// ---------------------------------------------------------------------------
// Fused residual + LayerNorm; optional secondary bf16 output.
// ---------------------------------------------------------------------------
template<int WB>
__global__ __launch_bounds__(256)
void ln_res_kernel(const float* __restrict__ in1, const float* __restrict__ in2,
                   const float* __restrict__ g, const float* __restrict__ bb,
                   float* __restrict__ out, short* __restrict__ ob)
{
    const int row = blockIdx.x;
    const int tid = threadIdx.x;
    const size_t base = (size_t)row * DMODEL + tid * 4;

    const float4 x1 = *(const float4*)(in1 + base);
    const float4 x2 = *(const float4*)(in2 + base);
    const float y0 = x1.x + x2.x, y1 = x1.y + x2.y;
    const float y2 = x1.z + x2.z, y3 = x1.w + x2.w;

    float s1 = y0 + y1 + y2 + y3;
    float s2 = y0 * y0 + y1 * y1 + y2 * y2 + y3 * y3;
    #pragma unroll
    for (int off = 1; off < 64; off <<= 1) {
        s1 += __shfl_xor(s1, off);
        s2 += __shfl_xor(s2, off);
    }
    __shared__ float red[8];
    if ((tid & 63) == 0) {
        red[tid >> 6]       = s1;
        red[4 + (tid >> 6)] = s2;
    }
    __syncthreads();
    s1 = red[0] + red[1] + red[2] + red[3];
    s2 = red[4] + red[5] + red[6] + red[7];

    const float mean = s1 * (1.0f / DMODEL);
    const float var  = s2 * (1.0f / DMODEL) - mean * mean;
    const float rstd = rsqrtf(var + 1e-5f);

    const float4 g4 = *(const float4*)(g + tid * 4);
    const float4 b4 = *(const float4*)(bb + tid * 4);
    float4 o;
    o.x = g4.x * ((y0 - mean) * rstd) + b4.x;
    o.y = g4.y * ((y1 - mean) * rstd) + b4.y;
    o.z = g4.z * ((y2 - mean) * rstd) + b4.z;
    o.w = g4.w * ((y3 - mean) * rstd) + b4.w;
    *(float4*)(out + base) = o;
    if (WB)
        *(ushort4*)(ob + base) = make_ushort4(f2bf(o.x), f2bf(o.y), f2bf(o.z), f2bf(o.w));
}

// ---------------------------------------------------------------------------
// kernel_launch
// ---------------------------------------------------------------------------
extern "C" void kernel_launch(void* const* d_in, const int* in_sizes, int n_in,
                              void* d_out, int out_size, void* d_ws, size_t ws_size,
                              hipStream_t stream)
{
    const float* x       = (const float*)d_in[0];
    const float* w_attn  = (const float*)d_in[1];
    const float* b_attn  = (const float*)d_in[2];
    const float* w_aproj = (const float*)d_in[3];
    const float* b_aproj = (const float*)d_in[4];
    const float* g1      = (const float*)d_in[5];
    const float* b1      = (const float*)d_in[6];
    const float* w_fc    = (const float*)d_in[7];
    const float* b_fc    = (const float*)d_in[8];
    const float* w_mproj = (const float*)d_in[9];
    const float* b_mproj = (const float*)d_in[10];
    const float* g2      = (const float*)d_in[11];
    const float* b2      = (const float*)d_in[12];
    float* outp = (float*)d_out;

    // Workspace (136 MB total, < 167.8 MB proven in Round 0):
    //   qkv_b bf16 [0, 48MB)    step 1 write, step 2 read
    //   hb    bf16 [0, 64MB)    step 5 write, step 6 read (qkv_b dead)
    //   nb    bf16 [64MB, 80MB) step 4 write, step 5 read
    //   t     fp32 [80MB, 112MB) proj outputs (steps 3, 6)
    //   wT    bf16 [112MB, 136MB) transposed weights
    // d_out doubles as bf16 scratch before step 4:
    //   xb [0,16MB) steps 0-1; ab [0,16MB) steps 2-3
    char* wsb = (char*)d_ws;
    short* qkvb = (short*)wsb;
    short* hb   = (short*)wsb;
    short* nb   = (short*)(wsb + (size_t)(64u << 20));
    float* t    = (float*)(wsb + (size_t)(80u << 20));
    short* wT_attn  = (short*)(wsb + (size_t)(112u << 20));
    short* wT_aproj = wT_attn + 3145728;
    short* wT_fc    = wT_aproj + 1048576;
    short* wT_mproj = wT_fc + 4194304;
    short* xb = (short*)d_out;
    short* ab = (short*)d_out;

    const int M = BATCH * S_CTX;  // 8192

    // 0) casts
    wcast_kernel<<<dim3(3 * DMODEL / 32, DMODEL / 32), 256, 0, stream>>>(w_attn, wT_attn, DMODEL, 3 * DMODEL);
    wcast_kernel<<<dim3(DMODEL / 32, DMODEL / 32), 256, 0, stream>>>(w_aproj, wT_aproj, DMODEL, DMODEL);
    wcast_kernel<<<dim3(DFF / 32, DMODEL / 32), 256, 0, stream>>>(w_fc, wT_fc, DMODEL, DFF);
    wcast_kernel<<<dim3(DMODEL / 32, DFF / 32), 256, 0, stream>>>(w_mproj, wT_mproj, DFF, DMODEL);
    cast_act_kernel<<<2048, 256, 0, stream>>>(x, xb, M * DMODEL / 4);

    // 1) qkv_b = bf16(x @ w_attn + b_attn)
    mfma_gemm_kernel<0, 1><<<dim3(3 * DMODEL / 128, M / 128), 256, 0, stream>>>(
        xb, wT_attn, b_attn, (void*)qkvb, M, 3 * DMODEL, DMODEL);

    // 2) ab = causal_attention(qkv_b)  (bf16, MFMA flash)
    attn_mfma_kernel<<<dim3(S_CTX / 64, NHEAD, BATCH), 256, 0, stream>>>(qkvb, ab);

    // 3) t = ab @ w_aproj + b_aproj  (fp32)
    mfma_gemm_kernel<0, 0><<<dim3(DMODEL / 128, M / 128), 256, 0, stream>>>(
        ab, wT_aproj, b_aproj, (void*)t, M, DMODEL, DMODEL);

    // 4) n = LayerNorm(x + t) -> d_out fp32 + nb bf16
    ln_res_kernel<1><<<M, 256, 0, stream>>>(x, t, g1, b1, outp, nb);

    // 5) hb = bf16(gelu(n @ w_fc + b_fc))
    mfma_gemm_kernel<1, 1><<<dim3(DFF / 128, M / 128), 256, 0, stream>>>(
        nb, wT_fc, b_fc, (void*)hb, M, DFF, DMODEL);

    // 6) t = hb @ w_mproj + b_mproj  (fp32)
    mfma_gemm_kernel<0, 0><<<dim3(DMODEL / 128, M / 128), 256, 0, stream>>>(
        hb, wT_mproj, b_mproj, (void*)t, M, DMODEL, DFF);

    // 7) out = LayerNorm(n + t)   (in-place row-safe)
    ln_res_kernel<0><<<M, 256, 0, stream>>>(outp, t, g2, b2, outp, nullptr);
}

// Round 10
// 639.839 us; speedup vs baseline: 5.5672x; 1.2018x over previous
//
#include <hip/hip_runtime.h>
#include <math.h>

#define S_CTX 2048
#define DMODEL 1024
#define NHEAD 16
#define HD 64
#define BATCH 4
#define DFF 4096

typedef __bf16 bf16x8 __attribute__((ext_vector_type(8)));
typedef float f32x4 __attribute__((ext_vector_type(4)));

// fp32 -> bf16 (round-to-nearest-even), bit-level
__device__ __forceinline__ unsigned short f2bf(float f) {
    union { float f; unsigned int u; } v; v.f = f;
    unsigned int u = v.u;
    u += 0x7fffu + ((u >> 16) & 1u);
    return (unsigned short)(u >> 16);
}

__device__ __forceinline__ float gelu_f(float v) {
    const float c = 0.7978845608028654f; // sqrt(2/pi)
    float u = c * (v + 0.044715f * v * v * v);
    return 0.5f * v * (1.0f + tanhf(u));
}

// async global->LDS, 16 bytes per lane; LDS dest = wave-uniform base + lane*16
#define GLOAD16(gsrc, ldst)                                                     \
    __builtin_amdgcn_global_load_lds(                                           \
        (const __attribute__((address_space(1))) void*)(gsrc),                  \
        (__attribute__((address_space(3))) void*)(ldst), 16, 0, 0)

// ---------------------------------------------------------------------------
// Weight cast+transpose: W fp32 [K,N] -> WT bf16 [N,K]
// ---------------------------------------------------------------------------
__global__ __launch_bounds__(256)
void wcast_kernel(const float* __restrict__ W, short* __restrict__ WT, int K, int N)
{
    __shared__ float tile[32][33];
    const int n0 = blockIdx.x * 32;
    const int k0 = blockIdx.y * 32;
    {
        const int r  = threadIdx.x >> 3;
        const int c4 = (threadIdx.x & 7) * 4;
        const float4 v = *(const float4*)&W[(size_t)(k0 + r) * N + n0 + c4];
        tile[r][c4 + 0] = v.x; tile[r][c4 + 1] = v.y;
        tile[r][c4 + 2] = v.z; tile[r][c4 + 3] = v.w;
    }
    __syncthreads();
    const int n  = threadIdx.x >> 3;
    const int k4 = (threadIdx.x & 7) * 4;
    ushort4 o = make_ushort4(f2bf(tile[k4 + 0][n]), f2bf(tile[k4 + 1][n]),
                             f2bf(tile[k4 + 2][n]), f2bf(tile[k4 + 3][n]));
    *(ushort4*)&WT[(size_t)(n0 + n) * K + k0 + k4] = o;
}

// ---------------------------------------------------------------------------
// Activation cast: fp32 -> bf16, vectorized
// ---------------------------------------------------------------------------
__global__ __launch_bounds__(256)
void cast_act_kernel(const float* __restrict__ in, short* __restrict__ out, int n4)
{
    int idx = blockIdx.x * blockDim.x + threadIdx.x;
    const int stride = gridDim.x * blockDim.x;
    for (; idx < n4; idx += stride) {
        const float4 v = ((const float4*)in)[idx];
        ((ushort4*)out)[idx] = make_ushort4(f2bf(v.x), f2bf(v.y), f2bf(v.z), f2bf(v.w));
    }
}

// ---------------------------------------------------------------------------
// bf16 MFMA GEMM (m97 structure): C[M,N] = A[M,K] @ BT[N,K]^T + bias
// (unchanged from the passing Round-3 kernel)
// ---------------------------------------------------------------------------
template<int GELU, int OBF16>
__global__ __launch_bounds__(256)
void mfma_gemm_kernel(const short* __restrict__ Ab, const short* __restrict__ BTb,
                      const float* __restrict__ bias, void* __restrict__ Cout,
                      int M, int N, int K)
{
    __shared__ short As[128 * 32];
    __shared__ short Bs[128 * 32];

    const int tid  = threadIdx.x;
    const int lane = tid & 63;
    const int wave = tid >> 6;
    const int wr   = (wave >> 1) * 64;
    const int wc   = (wave & 1) * 64;
    const int m0   = blockIdx.y * 128;
    const int n0   = blockIdx.x * 128;

    const int lrow = tid >> 2;           // 0..63
    const int slot = tid & 3;
    const int sw   = slot ^ (lrow & 3);  // pre-swizzled global source slot
    const short* Ag0 = Ab  + (size_t)(m0 + lrow) * K      + sw * 8;
    const short* Ag1 = Ab  + (size_t)(m0 + 64 + lrow) * K + sw * 8;
    const short* Bg0 = BTb + (size_t)(n0 + lrow) * K      + sw * 8;
    const short* Bg1 = BTb + (size_t)(n0 + 64 + lrow) * K + sw * 8;

    short* AsW = As + wave * 512;        // +2048 shorts = +4096 B = row 64
    short* BsW = Bs + wave * 512;

    f32x4 acc[4][4];
    #pragma unroll
    for (int i = 0; i < 4; ++i)
        #pragma unroll
        for (int j = 0; j < 4; ++j) acc[i][j] = (f32x4){0.f, 0.f, 0.f, 0.f};

    const int r  = lane & 15;
    const int kg = lane >> 4;
    int aoff[4], boff[4];
    #pragma unroll
    for (int m = 0; m < 4; ++m) {
        const int arow = wr + m * 16 + r;
        aoff[m] = arow * 32 + (kg ^ (arow & 3)) * 8;
        const int bcol = wc + m * 16 + r;
        boff[m] = bcol * 32 + (kg ^ (bcol & 3)) * 8;
    }

    for (int k0 = 0; k0 < K; k0 += 32) {
        __syncthreads();
        GLOAD16(Ag0 + k0, AsW);
        GLOAD16(Ag1 + k0, AsW + 2048);
        GLOAD16(Bg0 + k0, BsW);
        GLOAD16(Bg1 + k0, BsW + 2048);
        __syncthreads();

        bf16x8 af[4], bfr[4];
        #pragma unroll
        for (int m = 0; m < 4; ++m) af[m]  = *(const bf16x8*)(As + aoff[m]);
        #pragma unroll
        for (int n = 0; n < 4; ++n) bfr[n] = *(const bf16x8*)(Bs + boff[n]);
        #pragma unroll
        for (int m = 0; m < 4; ++m)
            #pragma unroll
            for (int n = 0; n < 4; ++n)
                acc[m][n] = __builtin_amdgcn_mfma_f32_16x16x32_bf16(
                    af[m], bfr[n], acc[m][n], 0, 0, 0);
    }

    // D: row = (lane>>4)*4 + reg, col = lane&15  [m89]
    const int crow0 = m0 + wr + kg * 4;
    const int ccol0 = n0 + wc + r;
    #pragma unroll
    for (int m = 0; m < 4; ++m) {
        #pragma unroll
        for (int i = 0; i < 4; ++i) {
            const size_t row = (size_t)(crow0 + m * 16 + i);
            #pragma unroll
            for (int n = 0; n < 4; ++n) {
                float v = acc[m][n][i] + bias[ccol0 + n * 16];
                if (GELU) v = gelu_f(v);
                if (OBF16) ((short*)Cout)[row * N + ccol0 + n * 16] = (short)f2bf(v);
                else       ((float*)Cout)[row * N + ccol0 + n * 16] = v;
            }
        }
    }
}

// ---------------------------------------------------------------------------
// MFMA flash attention v2.
// QBLK=128 (4 waves x 32 q-rows, Q in registers), KVBLK=64, K/V double-
// buffered with async prefetch, 1 barrier per k-tile. Causal pairing:
// block pairidx handles q-tiles {a, 15-a} -> uniform 34 k-tile-iters.
// Vt swizzle: stored unit' = (key>>2) ^ (((d>>2)&3)<<2)  (floor both sides).
// ---------------------------------------------------------------------------
__global__ __launch_bounds__(256)
void attn_mfma_kernel(const short* __restrict__ qkvb, short* __restrict__ out)
{
    __shared__ short Ks[2][64 * 64];   // [buf][key][d], slot^(key&7) swizzled
    __shared__ short Vt[2][64 * 64];   // [buf][d][key], unit-swizzled
    __shared__ short Pl[4][32 * 72];   // per-wave P rows (144B padded)

    const int tid  = threadIdx.x;
    const int lane = tid & 63;
    const int wave = tid >> 6;
    const int pairidx = blockIdx.x;    // 0..7
    const int h = blockIdx.y, b = blockIdx.z;
    const int r  = lane & 15;
    const int kg = lane >> 4;
    const size_t rstr  = 3 * DMODEL;
    const size_t bbase = (size_t)b * S_CTX;

    // V staging assignment: thread loads V[vkb..vkb+3][vd0..vd0+3]
    const int vd0 = (tid & 15) * 4;
    const int vkb = (tid >> 4) * 4;
    const short* vbase = qkvb + (bbase + vkb) * rstr + 2 * DMODEL + h * HD + vd0;
    // K staging assignment (per wave round rr: rows rr*32 + wave*8 .. +8)
    const int krl0 = wave * 8 + (lane >> 3);
    const int ksl  = lane & 7;
    const short* kbase0 = qkvb + bbase * rstr + DMODEL + h * HD;

    for (int half = 0; half < 2; ++half) {
        const int qt = half ? (15 - pairidx) : pairidx;
        const int q0 = qt * 128;
        const int nkt = 2 * qt + 2;

        // ---- Q fragments straight from global into registers ----
        bf16x8 qf[2][2];
        #pragma unroll
        for (int m = 0; m < 2; ++m)
            #pragma unroll
            for (int kb2 = 0; kb2 < 2; ++kb2)
                qf[m][kb2] = *(const bf16x8*)(qkvb
                    + (bbase + q0 + wave * 32 + m * 16 + r) * rstr
                    + h * HD + kb2 * 32 + kg * 8);

        float m_i[2][4], l_i[2][4];
        f32x4 o[2][4];
        #pragma unroll
        for (int m = 0; m < 2; ++m)
            #pragma unroll
            for (int i = 0; i < 4; ++i) {
                m_i[m][i] = -1e30f; l_i[m][i] = 0.0f;
                o[m][i] = (f32x4){0.f, 0.f, 0.f, 0.f};
            }

        // ---- prologue: stage tile 0 into buffers 0 ----
        {
            #pragma unroll
            for (int rr = 0; rr < 2; ++rr) {
                const int rl = rr * 32 + krl0;
                GLOAD16(kbase0 + (size_t)rl * rstr + ((ksl ^ (rl & 7)) * 8),
                        &Ks[0][(rr * 32 + wave * 8) * 64]);
            }
            ushort4 vr[4];
            #pragma unroll
            for (int j = 0; j < 4; ++j)
                vr[j] = *(const ushort4*)(vbase + (size_t)j * rstr);
            const unsigned short* vp = (const unsigned short*)vr;
            #pragma unroll
            for (int dd = 0; dd < 4; ++dd) {
                const int d  = vd0 + dd;
                const int up = (vkb >> 2) ^ (((d >> 2) & 3) << 2);
                *(ushort4*)((char*)&Vt[0][0] + d * 128 + up * 8) =
                    make_ushort4(vp[0 + dd], vp[4 + dd], vp[8 + dd], vp[12 + dd]);
            }
        }
        __syncthreads();

        for (int t = 0; t < nkt; ++t) {
            const int cur = t & 1;
            const bool pre = (t + 1 < nkt);
            ushort4 vr[4];
            // ---- prefetch next tile (async K -> LDS, V -> regs) ----
            if (pre) {
                const int k0n = (t + 1) * 64;
                #pragma unroll
                for (int rr = 0; rr < 2; ++rr) {
                    const int rl = rr * 32 + krl0;
                    GLOAD16(kbase0 + (size_t)(k0n + rl) * rstr + ((ksl ^ (rl & 7)) * 8),
                            &Ks[cur ^ 1][(rr * 32 + wave * 8) * 64]);
                }
                #pragma unroll
                for (int j = 0; j < 4; ++j)
                    vr[j] = *(const ushort4*)(vbase + (size_t)(k0n + j) * rstr);
            }

            // ---- S = Q K^T : 16 MFMA ----
            f32x4 s4[2][4];
            #pragma unroll
            for (int m = 0; m < 2; ++m)
                #pragma unroll
                for (int c = 0; c < 4; ++c) s4[m][c] = (f32x4){0.f, 0.f, 0.f, 0.f};
            __builtin_amdgcn_s_setprio(1);
            #pragma unroll
            for (int kb2 = 0; kb2 < 2; ++kb2) {
                #pragma unroll
                for (int c = 0; c < 4; ++c) {
                    const int krow = c * 16 + r;
                    const bf16x8 kf = *(const bf16x8*)(&Ks[cur][0]
                        + krow * 64 + (((kb2 * 4 + kg) ^ (krow & 7)) * 8));
                    #pragma unroll
                    for (int m = 0; m < 2; ++m)
                        s4[m][c] = __builtin_amdgcn_mfma_f32_16x16x32_bf16(
                            qf[m][kb2], kf, s4[m][c], 0, 0, 0);
                }
            }
            __builtin_amdgcn_s_setprio(0);

            // ---- mask + online softmax; P -> per-wave LDS (bf16) ----
            const int k0 = t * 64;
            #pragma unroll
            for (int m = 0; m < 2; ++m) {
                const int rowg0 = q0 + wave * 32 + m * 16 + kg * 4;
                #pragma unroll
                for (int reg = 0; reg < 4; ++reg) {
                    float sv[4];
                    #pragma unroll
                    for (int c = 0; c < 4; ++c) {
                        const int colg = k0 + c * 16 + r;
                        const float v = s4[m][c][reg] * 0.125f;
                        sv[c] = (colg <= rowg0 + reg) ? v : -1e30f;
                    }
                    float rmax = fmaxf(fmaxf(sv[0], sv[1]), fmaxf(sv[2], sv[3]));
                    rmax = fmaxf(rmax, __shfl_xor(rmax, 1));
                    rmax = fmaxf(rmax, __shfl_xor(rmax, 2));
                    rmax = fmaxf(rmax, __shfl_xor(rmax, 4));
                    rmax = fmaxf(rmax, __shfl_xor(rmax, 8));
                    const float mnew = fmaxf(m_i[m][reg], rmax);
                    const float sc   = __expf(m_i[m][reg] - mnew);
                    float rs = 0.0f;
                    #pragma unroll
                    for (int c = 0; c < 4; ++c) {
                        const float pc = __expf(sv[c] - mnew);
                        rs += pc;
                        Pl[wave][(m * 16 + kg * 4 + reg) * 72 + c * 16 + r] =
                            (short)f2bf(pc);
                    }
                    rs += __shfl_xor(rs, 1);
                    rs += __shfl_xor(rs, 2);
                    rs += __shfl_xor(rs, 4);
                    rs += __shfl_xor(rs, 8);
                    l_i[m][reg] = l_i[m][reg] * sc + rs;
                    m_i[m][reg] = mnew;
                    #pragma unroll
                    for (int db = 0; db < 4; ++db) o[m][db][reg] *= sc;
                }
            }

            // ---- O += P V : 16 MFMA ----
            __builtin_amdgcn_s_setprio(1);
            #pragma unroll
            for (int kb2 = 0; kb2 < 2; ++kb2) {
                bf16x8 pa[2];
                #pragma unroll
                for (int m = 0; m < 2; ++m)
                    pa[m] = *(const bf16x8*)(&Pl[wave][(m * 16 + r) * 72
                                                       + kb2 * 32 + kg * 8]);
                #pragma unroll
                for (int db = 0; db < 4; ++db) {
                    const int drow = db * 16 + r;
                    const bf16x8 bv = *(const bf16x8*)(&Vt[cur][0]
                        + drow * 64 + (((kb2 * 4 + kg) ^ (((drow >> 2) & 3) << 1)) * 8));
                    #pragma unroll
                    for (int m = 0; m < 2; ++m)
                        o[m][db] = __builtin_amdgcn_mfma_f32_16x16x32_bf16(
                            pa[m], bv, o[m][db], 0, 0, 0);
                }
            }
            __builtin_amdgcn_s_setprio(0);

            // ---- late transpose-write of prefetched V ----
            if (pre) {
                const unsigned short* vp = (const unsigned short*)vr;
                #pragma unroll
                for (int dd = 0; dd < 4; ++dd) {
                    const int d  = vd0 + dd;
                    const int up = (vkb >> 2) ^ (((d >> 2) & 3) << 2);
                    *(ushort4*)((char*)&Vt[cur ^ 1][0] + d * 128 + up * 8) =
                        make_ushort4(vp[0 + dd], vp[4 + dd], vp[8 + dd], vp[12 + dd]);
                }
            }
            __syncthreads();
        }

        // ---- normalize, write merged-head bf16 output ----
        #pragma unroll
        for (int m = 0; m < 2; ++m) {
            #pragma unroll
            for (int reg = 0; reg < 4; ++reg) {
                const float inv = 1.0f / l_i[m][reg];
                const size_t rowg = bbase + q0 + wave * 32 + m * 16 + kg * 4 + reg;
                #pragma unroll
                for (int db = 0; db < 4; ++db)
                    out[rowg * DMODEL + h * HD + db * 16 + r] =
                        (short)f2bf(o[m][db][reg] * inv);
            }
        }
    }
}

// ---------------------------------------------------------------------------
// Fused residual + LayerNorm; optional secondary bf16 output.
// ---------------------------------------------------------------------------
template<int WB>
__global__ __launch_bounds__(256)
void ln_res_kernel(const float* __restrict__ in1, const float* __restrict__ in2,
                   const float* __restrict__ g, const float* __restrict__ bb,
                   float* __restrict__ out, short* __restrict__ ob)
{
    const int row = blockIdx.x;
    const int tid = threadIdx.x;
    const size_t base = (size_t)row * DMODEL + tid * 4;

    const float4 x1 = *(const float4*)(in1 + base);
    const float4 x2 = *(const float4*)(in2 + base);
    const float y0 = x1.x + x2.x, y1 = x1.y + x2.y;
    const float y2 = x1.z + x2.z, y3 = x1.w + x2.w;

    float s1 = y0 + y1 + y2 + y3;
    float s2 = y0 * y0 + y1 * y1 + y2 * y2 + y3 * y3;
    #pragma unroll
    for (int off = 1; off < 64; off <<= 1) {
        s1 += __shfl_xor(s1, off);
        s2 += __shfl_xor(s2, off);
    }
    __shared__ float red[8];
    if ((tid & 63) == 0) {
        red[tid >> 6]       = s1;
        red[4 + (tid >> 6)] = s2;
    }
    __syncthreads();
    s1 = red[0] + red[1] + red[2] + red[3];
    s2 = red[4] + red[5] + red[6] + red[7];

    const float mean = s1 * (1.0f / DMODEL);
    const float var  = s2 * (1.0f / DMODEL) - mean * mean;
    const float rstd = rsqrtf(var + 1e-5f);

    const float4 g4 = *(const float4*)(g + tid * 4);
    const float4 b4 = *(const float4*)(bb + tid * 4);
    float4 o;
    o.x = g4.x * ((y0 - mean) * rstd) + b4.x;
    o.y = g4.y * ((y1 - mean) * rstd) + b4.y;
    o.z = g4.z * ((y2 - mean) * rstd) + b4.z;
    o.w = g4.w * ((y3 - mean) * rstd) + b4.w;
    *(float4*)(out + base) = o;
    if (WB)
        *(ushort4*)(ob + base) = make_ushort4(f2bf(o.x), f2bf(o.y), f2bf(o.z), f2bf(o.w));
}

// ---------------------------------------------------------------------------
// kernel_launch
// ---------------------------------------------------------------------------
extern "C" void kernel_launch(void* const* d_in, const int* in_sizes, int n_in,
                              void* d_out, int out_size, void* d_ws, size_t ws_size,
                              hipStream_t stream)
{
    const float* x       = (const float*)d_in[0];
    const float* w_attn  = (const float*)d_in[1];
    const float* b_attn  = (const float*)d_in[2];
    const float* w_aproj = (const float*)d_in[3];
    const float* b_aproj = (const float*)d_in[4];
    const float* g1      = (const float*)d_in[5];
    const float* b1      = (const float*)d_in[6];
    const float* w_fc    = (const float*)d_in[7];
    const float* b_fc    = (const float*)d_in[8];
    const float* w_mproj = (const float*)d_in[9];
    const float* b_mproj = (const float*)d_in[10];
    const float* g2      = (const float*)d_in[11];
    const float* b2      = (const float*)d_in[12];
    float* outp = (float*)d_out;

    // Workspace (136 MB total, < 167.8 MB proven):
    //   qkv_b bf16 [0, 48MB)      step 1 write, step 2 read
    //   hb    bf16 [0, 64MB)      step 5 write, step 6 read (qkv_b dead)
    //   nb    bf16 [64MB, 80MB)   step 4 write, step 5 read
    //   t     fp32 [80MB, 112MB)  proj outputs (steps 3, 6)
    //   wT    bf16 [112MB, 136MB) transposed weights
    // d_out doubles as bf16 scratch before step 4: xb / ab
    char* wsb = (char*)d_ws;
    short* qkvb = (short*)wsb;
    short* hb   = (short*)wsb;
    short* nb   = (short*)(wsb + (size_t)(64u << 20));
    float* t    = (float*)(wsb + (size_t)(80u << 20));
    short* wT_attn  = (short*)(wsb + (size_t)(112u << 20));
    short* wT_aproj = wT_attn + 3145728;
    short* wT_fc    = wT_aproj + 1048576;
    short* wT_mproj = wT_fc + 4194304;
    short* xb = (short*)d_out;
    short* ab = (short*)d_out;

    const int M = BATCH * S_CTX;  // 8192

    // 0) casts
    wcast_kernel<<<dim3(3 * DMODEL / 32, DMODEL / 32), 256, 0, stream>>>(w_attn, wT_attn, DMODEL, 3 * DMODEL);
    wcast_kernel<<<dim3(DMODEL / 32, DMODEL / 32), 256, 0, stream>>>(w_aproj, wT_aproj, DMODEL, DMODEL);
    wcast_kernel<<<dim3(DFF / 32, DMODEL / 32), 256, 0, stream>>>(w_fc, wT_fc, DMODEL, DFF);
    wcast_kernel<<<dim3(DMODEL / 32, DFF / 32), 256, 0, stream>>>(w_mproj, wT_mproj, DFF, DMODEL);
    cast_act_kernel<<<2048, 256, 0, stream>>>(x, xb, M * DMODEL / 4);

    // 1) qkv_b = bf16(x @ w_attn + b_attn)
    mfma_gemm_kernel<0, 1><<<dim3(3 * DMODEL / 128, M / 128), 256, 0, stream>>>(
        xb, wT_attn, b_attn, (void*)qkvb, M, 3 * DMODEL, DMODEL);

    // 2) ab = causal_attention(qkv_b)  (bf16, MFMA flash v2, paired q-tiles)
    attn_mfma_kernel<<<dim3(8, NHEAD, BATCH), 256, 0, stream>>>(qkvb, ab);

    // 3) t = ab @ w_aproj + b_aproj  (fp32)
    mfma_gemm_kernel<0, 0><<<dim3(DMODEL / 128, M / 128), 256, 0, stream>>>(
        ab, wT_aproj, b_aproj, (void*)t, M, DMODEL, DMODEL);

    // 4) n = LayerNorm(x + t) -> d_out fp32 + nb bf16
    ln_res_kernel<1><<<M, 256, 0, stream>>>(x, t, g1, b1, outp, nb);

    // 5) hb = bf16(gelu(n @ w_fc + b_fc))
    mfma_gemm_kernel<1, 1><<<dim3(DFF / 128, M / 128), 256, 0, stream>>>(
        nb, wT_fc, b_fc, (void*)hb, M, DFF, DMODEL);

    // 6) t = hb @ w_mproj + b_mproj  (fp32)
    mfma_gemm_kernel<0, 0><<<dim3(DMODEL / 128, M / 128), 256, 0, stream>>>(
        hb, wT_mproj, b_mproj, (void*)t, M, DMODEL, DFF);

    // 7) out = LayerNorm(n + t)   (in-place row-safe)
    ln_res_kernel<0><<<M, 256, 0, stream>>>(outp, t, g2, b2, outp, nullptr);
}